// Round 6
// baseline (5133.089 us; speedup 1.0000x reference)
//
#include <hip/hip_runtime.h>

#define NS 512
#define NA 256
#define PGD_ITERS 300
#define POWER_ITERS 30

typedef _Float16 f16;
typedef __attribute__((ext_vector_type(4))) _Float16 f16x4;
typedef __attribute__((ext_vector_type(8))) _Float16 f16x8;
typedef __attribute__((ext_vector_type(4))) float f32x4;

// LDS layout (bytes, all 16B aligned). Total 43,328 B.
#define CSTR 260            // f32 staging row stride (elems): 16 rows x 260
#define TSTR 24             // f16 C^T tile row stride (elems) = 48 B (16 used + pad)
#define OFF_CH  16640       // STG: 16*260*4 = 16640
#define OFF_CL  28928       // CH:  256*24*2 = 12288
#define OFF_ZF  41216       // CL:  12288
#define OFF_VV  42240       // ZF:  256 f32
#define OFF_RED 43264       // VV:  256 f32
#define LDS_BYTES 43328     // RED: 16 f32

__device__ __forceinline__ float sel8(const f32x4& a, const f32x4& b, int iw, int pw) {
  // select a/b[pw] with all-constant vector component indices (rule #20 safe)
  const float v0 = iw ? b[0] : a[0];
  const float v1 = iw ? b[1] : a[1];
  const float v2 = iw ? b[2] : a[2];
  const float v3 = iw ? b[3] : a[3];
  return (pw == 0) ? v0 : (pw == 1) ? v1 : (pw == 2) ? v2 : v3;
}

__global__ __launch_bounds__(512) void markowitz_kernel(
    const float* __restrict__ rets, const float* __restrict__ cov,
    const float* __restrict__ gam,  const float* __restrict__ alp,
    float* __restrict__ out)
{
  __shared__ char smem[LDS_BYTES] __attribute__((aligned(16)));
  float* STG = (float*)smem;
  f16*   CH  = (f16*)(smem + OFF_CH);
  f16*   CL  = (f16*)(smem + OFF_CL);
  float* ZF  = (float*)(smem + OFF_ZF);
  float* VV  = (float*)(smem + OFF_VV);
  float* RED = (float*)(smem + OFF_RED);

  const int b    = blockIdx.x;
  const int t    = threadIdx.x;
  const int lane = t & 63;
  const int wv   = t >> 6;          // wave 0..7
  const int lm   = lane & 15;       // MFMA col-within-tile / frag row
  const int hq   = lane >> 4;       // MFMA k-group / row-group

  const float g  = gam[b];
  const float aa = fabsf(alp[b]);
  const float* __restrict__ C = cov + (size_t)b * (NA * NA);

  // Writer-lane mapping: lanes lm<8 own one Q-row each:
  // ii = lm>>2, p = lm&3, row = 16*(wv+8*ii) + 4*hq + p. Covers 0..255 once.
  const bool wr   = (lm < 8);
  const int  ii_w = (lm >> 2) & 1;
  const int  p_w  = lm & 3;
  const int  row_w = 16 * (wv + 8 * ii_w) + 4 * hq + p_w;
  const float rr_w = wr ? rets[b * NA + row_w] : 0.f;

  // ===== Phase 1: Q = (gC)^T(gC) + |a|I, ~f32-exact via compensated f16 syrk =====
  // acc[ii][J][p] = Q[16*(wv+8ii) + 4*hq + p][16*J + lm]   (m89 C/D layout)
  f32x4 acc[2][16];
  #pragma unroll
  for (int i = 0; i < 2; ++i)
    #pragma unroll
    for (int j = 0; j < 16; ++j)
      acc[i][j] = f32x4{0.f, 0.f, 0.f, 0.f};

  #pragma unroll 1
  for (int kb = 0; kb < 16; ++kb) {
    { // stage 16x256 f32 (gamma-folded), coalesced
      const int kk = t >> 5;          // 0..15
      const int ib = (t & 31) << 3;   // 0,8,...,248
      const float* src = C + (size_t)(kb * 16 + kk) * NA + ib;
      float* dst = STG + kk * CSTR + ib;
      float4 c0 = *(const float4*)(src);
      float4 c1 = *(const float4*)(src + 4);
      *(float4*)(dst)     = make_float4(c0.x * g, c0.y * g, c0.z * g, c0.w * g);
      *(float4*)(dst + 4) = make_float4(c1.x * g, c1.y * g, c1.z * g, c1.w * g);
    }
    __syncthreads();
    { // transpose + hi/lo split into C^T tiles (256 cols x 16 k)
      const int ti = t & 255;
      const int th = t >> 8;          // k-half 0/1
      f16x8 vh, vlo;
      #pragma unroll
      for (int s2 = 0; s2 < 8; ++s2) {
        const float x = STG[(8 * th + s2) * CSTR + ti];
        const f16 h = (f16)x;
        vh[s2]  = h;
        vlo[s2] = (f16)(x - (float)h);   // exact residual
      }
      *(f16x8*)(CH + ti * TSTR + 8 * th) = vh;    // byte 48*ti+16*th, 16B aligned
      *(f16x8*)(CL + ti * TSTR + 8 * th) = vlo;
    }
    __syncthreads();
    // Q += H^T H + H^T L + L^T H  (L^T L ~ 2^-22, negligible)
    #pragma unroll
    for (int ii = 0; ii < 2; ++ii) {
      const int I = wv + 8 * ii;
      const f16x4 aH = *(const f16x4*)(CH + (16 * I + lm) * TSTR + 4 * hq);
      const f16x4 aL = *(const f16x4*)(CL + (16 * I + lm) * TSTR + 4 * hq);
      #pragma unroll
      for (int J = 0; J < 16; ++J) {
        const f16x4 bH = *(const f16x4*)(CH + (16 * J + lm) * TSTR + 4 * hq);
        const f16x4 bL = *(const f16x4*)(CL + (16 * J + lm) * TSTR + 4 * hq);
        acc[ii][J] = __builtin_amdgcn_mfma_f32_16x16x16f16(aH, bH, acc[ii][J], 0, 0, 0);
        acc[ii][J] = __builtin_amdgcn_mfma_f32_16x16x16f16(aH, bL, acc[ii][J], 0, 0, 0);
        acc[ii][J] = __builtin_amdgcn_mfma_f32_16x16x16f16(aL, bH, acc[ii][J], 0, 0, 0);
      }
    }
    // next staging writes STG (disjoint from CH/CL); post-stage barrier
    // orders the CH/CL overwrite vs these MFMA reads.
  }

  // add |alpha| to the diagonal (row==col <=> J==I and lm==4*hq+p)
  #pragma unroll
  for (int J = 0; J < 16; ++J) {
    #pragma unroll
    for (int p = 0; p < 4; ++p) {
      if (J == wv     && lm == 4 * hq + p) acc[0][J][p] += aa;
      if (J == wv + 8 && lm == 4 * hq + p) acc[1][J][p] += aa;
    }
  }

  if (t < 256) ZF[t] = 1.f;   // power-iteration b0 = ones
  __syncthreads();

  // ===== register matvec: y = Q z, z read from ZF (broadcast LDS reads) =====
  auto matvec = [&](f32x4& y0, f32x4& y1) {
    y0 = f32x4{0.f, 0.f, 0.f, 0.f};
    y1 = f32x4{0.f, 0.f, 0.f, 0.f};
    #pragma unroll
    for (int J = 0; J < 16; ++J) {
      const float zx = ZF[16 * J + lm];
      #pragma unroll
      for (int c = 0; c < 4; ++c) {
        y0[c] += acc[0][J][c] * zx;
        y1[c] += acc[1][J][c] * zx;
      }
    }
    #pragma unroll
    for (int d = 1; d <= 8; d <<= 1) {
      #pragma unroll
      for (int c = 0; c < 4; ++c) {
        y0[c] += __shfl_xor(y0[c], d);
        y1[c] += __shfl_xor(y1[c], d);
      }
    }
  };

  // ===== Phase 2: power iteration + Rayleigh step size =====
  float step;
  {
    #pragma unroll 1
    for (int pi = 0; pi < POWER_ITERS; ++pi) {
      f32x4 y0, y1; matvec(y0, y1);
      float local = 0.f;
      #pragma unroll
      for (int c = 0; c < 4; ++c) local += y0[c] * y0[c] + y1[c] * y1[c];
      local += __shfl_xor(local, 16);
      local += __shfl_xor(local, 32);
      if (lane == 0) RED[wv] = local;
      __syncthreads();
      float nrm = 0.f;
      #pragma unroll
      for (int q = 0; q < 8; ++q) nrm += RED[q];
      const float rb = 1.f / (sqrtf(nrm) + 1e-12f);
      if (wr) ZF[row_w] = sel8(y0, y1, ii_w, p_w) * rb;
      __syncthreads();
    }
    f32x4 y0, y1; matvec(y0, y1);
    float local = 0.f;
    #pragma unroll
    for (int p = 0; p < 4; ++p) {
      local += ZF[16 * wv + 4 * hq + p] * y0[p];
      local += ZF[16 * (wv + 8) + 4 * hq + p] * y1[p];
    }
    local += __shfl_xor(local, 16);
    local += __shfl_xor(local, 32);
    if (lane == 0) RED[wv] = local;
    __syncthreads();
    float lam = 0.f;
    #pragma unroll
    for (int q = 0; q < 8; ++q) lam += RED[q];
    step = 1.f / (2.f * lam + 1e-6f);
  }

  // ===== Phase 3: FISTA =====
  if (wr) ZF[row_w] = 1.f / 256.f;
  float zw = 1.f / 256.f, ww = 1.f / 256.f, tt = 1.f;
  float tauw = 1e30f;
  __syncthreads();

  #pragma unroll 1
  for (int it = 0; it < PGD_ITERS; ++it) {
    f32x4 y0, y1; matvec(y0, y1);
    float vr = 0.f;
    if (wr) {
      const float ysel = sel8(y0, y1, ii_w, p_w);
      vr = zw - step * (2.f * ysel - rr_w);
      VV[row_w] = vr;
    }
    __syncthreads();

    // projection onto {w: sum=1, 0<=w<=1}; wave-redundant, scale-free
    // bracket [max(v)-1, max(v)] (s(mx-1)>=1 from top asset alone; s(mx)=0)
    const f32x4 vl = *(const f32x4*)(VV + 4 * lane);
    float mx = fmaxf(fmaxf(vl[0], vl[1]), fmaxf(vl[2], vl[3]));
    #pragma unroll
    for (int d = 1; d < 64; d <<= 1) mx = fmaxf(mx, __shfl_xor(mx, d));

    float lo = mx - 1.0f, hi = mx;
    float tau = tauw;
    if (!(tau > lo && tau < hi)) tau = 0.5f * (lo + hi);

    #pragma unroll 1
    for (int nit = 0; nit < 30; ++nit) {
      float s = 0.f, kc = 0.f;
      #pragma unroll
      for (int j = 0; j < 4; ++j) {
        const float x = vl[j] - tau;
        s  += fminf(fmaxf(x, 0.f), 1.0f);
        kc += (x > 0.f && x < 1.0f) ? 1.f : 0.f;
      }
      #pragma unroll
      for (int d = 1; d < 64; d <<= 1) {
        s  += __shfl_xor(s, d);
        kc += __shfl_xor(kc, d);
      }
      const float f = s - 1.f;
      if (fabsf(f) <= 1e-6f) break;
      if (f > 0.f) lo = tau; else hi = tau;
      if (hi - lo < 1e-7f) { tau = 0.5f * (lo + hi); break; }
      const float tn = (kc > 0.5f) ? (tau + f / kc) : (0.5f * (lo + hi));
      tau = (tn > lo && tn < hi) ? tn : 0.5f * (lo + hi);
    }
    tauw = tau;

    const float tnew = 0.5f * (1.f + sqrtf(1.f + 4.f * tt * tt));
    if (wr) {
      const float wn = fminf(fmaxf(vr - tau, 0.f), 1.0f);
      const float zn = wn + ((tt - 1.f) / tnew) * (wn - ww);
      ww = wn; zw = zn;
      ZF[row_w] = zn;
    }
    tt = tnew;
    __syncthreads();
  }

  // Output dtype is FLOAT32 (reference returns f32; the test label's "bf16"
  // text is a hard-coded format string, not a dtype indicator).
  if (wr) out[(size_t)b * NA + row_w] = ww;
}

extern "C" void kernel_launch(void* const* d_in, const int* in_sizes, int n_in,
                              void* d_out, int out_size, void* d_ws, size_t ws_size,
                              hipStream_t stream) {
  (void)in_sizes; (void)n_in; (void)out_size; (void)d_ws; (void)ws_size;
  const float* rets = (const float*)d_in[0];
  const float* cov  = (const float*)d_in[1];
  const float* gam  = (const float*)d_in[2];
  const float* alp  = (const float*)d_in[3];
  float* out = (float*)d_out;
  hipLaunchKernelGGL(markowitz_kernel, dim3(NS), dim3(512), 0, stream,
                     rets, cov, gam, alp, out);
}

// Round 7
// 3024.999 us; speedup vs baseline: 1.6969x; 1.6969x over previous
//
#include <hip/hip_runtime.h>

#define NS 512
#define NA 256
#define PGD_ITERS 300
#define POWER_ITERS 30

typedef _Float16 f16;
typedef __attribute__((ext_vector_type(4))) _Float16 f16x4;
typedef __attribute__((ext_vector_type(8))) _Float16 f16x8;
typedef __attribute__((ext_vector_type(4))) float f32x4;

// LDS layout (bytes, all 16B aligned). Total 43,328 B.
#define CSTR 260            // f32 staging row stride (elems): 16 rows x 260
#define TSTR 24             // f16 C^T tile row stride (elems) = 48 B (16 used + pad)
#define OFF_CH  16640       // STG: 16*260*4 = 16640
#define OFF_CL  28928       // CH:  256*24*2 = 12288
#define OFF_ZF  41216       // CL:  12288
#define OFF_VV  42240       // ZF:  256 f32
#define OFF_RED 43264       // VV:  256 f32
#define LDS_BYTES 43328     // RED: 16 f32

__device__ __forceinline__ float sel8(const f32x4& a, const f32x4& b, int iw, int pw) {
  // select a/b[pw] with all-constant vector component indices (rule #20 safe)
  const float v0 = iw ? b[0] : a[0];
  const float v1 = iw ? b[1] : a[1];
  const float v2 = iw ? b[2] : a[2];
  const float v3 = iw ? b[3] : a[3];
  return (pw == 0) ? v0 : (pw == 1) ? v1 : (pw == 2) ? v2 : v3;
}

__global__ __launch_bounds__(512) void markowitz_kernel(
    const float* __restrict__ rets, const float* __restrict__ cov,
    const float* __restrict__ gam,  const float* __restrict__ alp,
    float* __restrict__ out)
{
  __shared__ char smem[LDS_BYTES] __attribute__((aligned(16)));
  float* STG = (float*)smem;
  f16*   CH  = (f16*)(smem + OFF_CH);
  f16*   CL  = (f16*)(smem + OFF_CL);
  float* ZF  = (float*)(smem + OFF_ZF);
  float* VV  = (float*)(smem + OFF_VV);
  float* RED = (float*)(smem + OFF_RED);

  const int b    = blockIdx.x;
  const int t    = threadIdx.x;
  const int lane = t & 63;
  const int wv   = t >> 6;          // wave 0..7
  const int lm   = lane & 15;       // MFMA col-within-tile / frag row
  const int hq   = lane >> 4;       // MFMA k-group / row-group

  const float g  = gam[b];
  const float aa = fabsf(alp[b]);
  const float* __restrict__ C = cov + (size_t)b * (NA * NA);

  // Writer-lane mapping: lanes lm<8 own one Q-row each:
  // ii = lm>>2, p = lm&3, row = 16*(wv+8*ii) + 4*hq + p. Covers 0..255 once.
  const bool wr   = (lm < 8);
  const int  ii_w = (lm >> 2) & 1;
  const int  p_w  = lm & 3;
  const int  row_w = 16 * (wv + 8 * ii_w) + 4 * hq + p_w;
  const float rr_w = wr ? rets[b * NA + row_w] : 0.f;

  // ===== Phase 1: Q = (gC)^T(gC) + |a|I, ~f32-exact via compensated f16 syrk =====
  // acc[ii][J][p] = Q[16*(wv+8ii) + 4*hq + p][16*J + lm]   (m89 C/D layout)
  f32x4 acc[2][16];
  #pragma unroll
  for (int i = 0; i < 2; ++i)
    #pragma unroll
    for (int j = 0; j < 16; ++j)
      acc[i][j] = f32x4{0.f, 0.f, 0.f, 0.f};

  #pragma unroll 1
  for (int kb = 0; kb < 16; ++kb) {
    { // stage 16x256 f32 (gamma-folded), coalesced
      const int kk = t >> 5;          // 0..15
      const int ib = (t & 31) << 3;   // 0,8,...,248
      const float* src = C + (size_t)(kb * 16 + kk) * NA + ib;
      float* dst = STG + kk * CSTR + ib;
      float4 c0 = *(const float4*)(src);
      float4 c1 = *(const float4*)(src + 4);
      *(float4*)(dst)     = make_float4(c0.x * g, c0.y * g, c0.z * g, c0.w * g);
      *(float4*)(dst + 4) = make_float4(c1.x * g, c1.y * g, c1.z * g, c1.w * g);
    }
    __syncthreads();
    { // transpose + hi/lo split into C^T tiles (256 cols x 16 k)
      const int ti = t & 255;
      const int th = t >> 8;          // k-half 0/1
      f16x8 vh, vlo;
      #pragma unroll
      for (int s2 = 0; s2 < 8; ++s2) {
        const float x = STG[(8 * th + s2) * CSTR + ti];
        const f16 h = (f16)x;
        vh[s2]  = h;
        vlo[s2] = (f16)(x - (float)h);   // exact residual
      }
      *(f16x8*)(CH + ti * TSTR + 8 * th) = vh;    // byte 48*ti+16*th, 16B aligned
      *(f16x8*)(CL + ti * TSTR + 8 * th) = vlo;
    }
    __syncthreads();
    // Q += H^T H + H^T L + L^T H  (L^T L ~ 2^-22, negligible)
    #pragma unroll
    for (int ii = 0; ii < 2; ++ii) {
      const int I = wv + 8 * ii;
      const f16x4 aH = *(const f16x4*)(CH + (16 * I + lm) * TSTR + 4 * hq);
      const f16x4 aL = *(const f16x4*)(CL + (16 * I + lm) * TSTR + 4 * hq);
      #pragma unroll
      for (int J = 0; J < 16; ++J) {
        const f16x4 bH = *(const f16x4*)(CH + (16 * J + lm) * TSTR + 4 * hq);
        const f16x4 bL = *(const f16x4*)(CL + (16 * J + lm) * TSTR + 4 * hq);
        acc[ii][J] = __builtin_amdgcn_mfma_f32_16x16x16f16(aH, bH, acc[ii][J], 0, 0, 0);
        acc[ii][J] = __builtin_amdgcn_mfma_f32_16x16x16f16(aH, bL, acc[ii][J], 0, 0, 0);
        acc[ii][J] = __builtin_amdgcn_mfma_f32_16x16x16f16(aL, bH, acc[ii][J], 0, 0, 0);
      }
    }
    // next staging writes STG (disjoint from CH/CL); post-stage barrier
    // orders the CH/CL overwrite vs these MFMA reads.
  }

  // add |alpha| to the diagonal (row==col <=> J==I and lm==4*hq+p)
  #pragma unroll
  for (int J = 0; J < 16; ++J) {
    #pragma unroll
    for (int p = 0; p < 4; ++p) {
      if (J == wv     && lm == 4 * hq + p) acc[0][J][p] += aa;
      if (J == wv + 8 && lm == 4 * hq + p) acc[1][J][p] += aa;
    }
  }

  if (t < 256) ZF[t] = 1.f;   // power-iteration b0 = ones
  __syncthreads();

  // ===== register matvec: y = Q z, z read from ZF (broadcast LDS reads) =====
  auto matvec = [&](f32x4& y0, f32x4& y1) {
    y0 = f32x4{0.f, 0.f, 0.f, 0.f};
    y1 = f32x4{0.f, 0.f, 0.f, 0.f};
    #pragma unroll
    for (int J = 0; J < 16; ++J) {
      const float zx = ZF[16 * J + lm];
      #pragma unroll
      for (int c = 0; c < 4; ++c) {
        y0[c] += acc[0][J][c] * zx;
        y1[c] += acc[1][J][c] * zx;
      }
    }
    #pragma unroll
    for (int d = 1; d <= 8; d <<= 1) {
      #pragma unroll
      for (int c = 0; c < 4; ++c) {
        y0[c] += __shfl_xor(y0[c], d);
        y1[c] += __shfl_xor(y1[c], d);
      }
    }
  };

  // ===== Phase 2: power iteration + Rayleigh step size =====
  float step;
  {
    #pragma unroll 1
    for (int pi = 0; pi < POWER_ITERS; ++pi) {
      f32x4 y0, y1; matvec(y0, y1);
      float local = 0.f;
      #pragma unroll
      for (int c = 0; c < 4; ++c) local += y0[c] * y0[c] + y1[c] * y1[c];
      local += __shfl_xor(local, 16);
      local += __shfl_xor(local, 32);
      if (lane == 0) RED[wv] = local;
      __syncthreads();
      float nrm = 0.f;
      #pragma unroll
      for (int q = 0; q < 8; ++q) nrm += RED[q];
      const float rb = 1.f / (sqrtf(nrm) + 1e-12f);
      if (wr) ZF[row_w] = sel8(y0, y1, ii_w, p_w) * rb;
      __syncthreads();
    }
    f32x4 y0, y1; matvec(y0, y1);
    float local = 0.f;
    #pragma unroll
    for (int p = 0; p < 4; ++p) {
      local += ZF[16 * wv + 4 * hq + p] * y0[p];
      local += ZF[16 * (wv + 8) + 4 * hq + p] * y1[p];
    }
    local += __shfl_xor(local, 16);
    local += __shfl_xor(local, 32);
    if (lane == 0) RED[wv] = local;
    __syncthreads();
    float lam = 0.f;
    #pragma unroll
    for (int q = 0; q < 8; ++q) lam += RED[q];
    step = 1.f / (2.f * lam + 1e-6f);
  }

  // ===== Phase 3: FISTA =====
  if (wr) ZF[row_w] = 1.f / 256.f;
  float zw = 1.f / 256.f, ww = 1.f / 256.f, tt = 1.f;
  float tauw = 1e30f;
  __syncthreads();

  const int li = lane & 31;   // duplicate-half v layout: 8 v's per lane

  #pragma unroll 1
  for (int it = 0; it < PGD_ITERS; ++it) {
    f32x4 y0, y1; matvec(y0, y1);
    float vr = 0.f;
    if (wr) {
      const float ysel = sel8(y0, y1, ii_w, p_w);
      vr = zw - step * (2.f * ysel - rr_w);
      VV[row_w] = vr;
    }
    __syncthreads();

    // Projection onto {w: sum=1, 0<=w<=1}. Wave-redundant; both 32-lane
    // halves hold identical copies of all 256 v's (8/lane) so reductions
    // need only 5 shuffle steps and stay bitwise-uniform across the wave.
    // Scale-free bracket: root tau* in [max(v)-1, max(v)].
    const f32x4 va = *(const f32x4*)(VV + 8 * li);
    const f32x4 vb = *(const f32x4*)(VV + 8 * li + 4);

    float lo = -1e30f, hi = 1e30f;
    float tau = tauw;
    #pragma unroll 1
    for (int nit = 0; nit < 12; ++nit) {
      float s = 0.f, kc = 0.f;
      #pragma unroll
      for (int j = 0; j < 4; ++j) {
        float x = va[j] - tau;
        s  += fminf(fmaxf(x, 0.f), 1.0f);
        kc += (x > 0.f && x < 1.0f) ? 1.f : 0.f;
        x = vb[j] - tau;
        s  += fminf(fmaxf(x, 0.f), 1.0f);
        kc += (x > 0.f && x < 1.0f) ? 1.f : 0.f;
      }
      if (nit == 0) {
        // fuse the global max as a 3rd independent shuffle chain
        float pm = fmaxf(fmaxf(fmaxf(va[0], va[1]), fmaxf(va[2], va[3])),
                         fmaxf(fmaxf(vb[0], vb[1]), fmaxf(vb[2], vb[3])));
        #pragma unroll
        for (int d = 1; d < 32; d <<= 1) {
          s  += __shfl_xor(s, d);
          kc += __shfl_xor(kc, d);
          pm = fmaxf(pm, __shfl_xor(pm, d));
        }
        lo = pm - 1.0f; hi = pm;
        if (!(tau > lo && tau < hi)) { tau = 0.5f * (lo + hi); continue; }
      } else {
        #pragma unroll
        for (int d = 1; d < 32; d <<= 1) {
          s  += __shfl_xor(s, d);
          kc += __shfl_xor(kc, d);
        }
      }
      const float f = s - 1.f;
      if (fabsf(f) <= 1e-5f) break;           // achievable in f32 (noise ~3e-6)
      if (f > 0.f) lo = tau; else hi = tau;
      if (hi - lo < 1e-7f) break;
      const float tn = (kc > 0.5f) ? (tau + f / kc) : (0.5f * (lo + hi));
      const float tc = (tn > lo && tn < hi) ? tn : 0.5f * (lo + hi);
      if (tc == tau) break;                   // numerical fixed point
      tau = tc;
    }
    tauw = tau;

    const float tnew = 0.5f * (1.f + sqrtf(1.f + 4.f * tt * tt));
    if (wr) {
      const float wn = fminf(fmaxf(vr - tau, 0.f), 1.0f);
      const float zn = wn + ((tt - 1.f) / tnew) * (wn - ww);
      ww = wn; zw = zn;
      ZF[row_w] = zn;
    }
    tt = tnew;
    __syncthreads();
  }

  // Output dtype is FLOAT32 (reference returns f32).
  if (wr) out[(size_t)b * NA + row_w] = ww;
}

extern "C" void kernel_launch(void* const* d_in, const int* in_sizes, int n_in,
                              void* d_out, int out_size, void* d_ws, size_t ws_size,
                              hipStream_t stream) {
  (void)in_sizes; (void)n_in; (void)out_size; (void)d_ws; (void)ws_size;
  const float* rets = (const float*)d_in[0];
  const float* cov  = (const float*)d_in[1];
  const float* gam  = (const float*)d_in[2];
  const float* alp  = (const float*)d_in[3];
  float* out = (float*)d_out;
  hipLaunchKernelGGL(markowitz_kernel, dim3(NS), dim3(512), 0, stream,
                     rets, cov, gam, alp, out);
}

// Round 8
// 2989.773 us; speedup vs baseline: 1.7169x; 1.0118x over previous
//
#include <hip/hip_runtime.h>

#define NS 512
#define NA 256
#define PGD_ITERS 300
#define POWER_ITERS 30

typedef _Float16 f16;
typedef __attribute__((ext_vector_type(4))) _Float16 f16x4;
typedef __attribute__((ext_vector_type(8))) _Float16 f16x8;
typedef __attribute__((ext_vector_type(4))) float f32x4;

// LDS layout (bytes). STG/CH/CL only live during the syrk; YY0/YY1 are the
// double-buffered y-exchange (1 KiB each) used by power + FISTA phases.
#define CSTR 260            // f32 staging row stride (elems)
#define TSTR 24             // f16 C^T tile row stride (elems) = 48 B
#define OFF_CH  16640       // STG: 16*260*4
#define OFF_CL  28928       // CH:  256*24*2
#define OFF_YY0 41216       // CL:  256*24*2
#define OFF_YY1 42240       // YY0: 256 f32
#define LDS_BYTES 43264     // YY1: 256 f32

// ds_swizzle with immediate pattern: no VALU address math, conflict-free.
template<int IMM>
__device__ __forceinline__ float swzf(float x) {
  return __int_as_float(__builtin_amdgcn_ds_swizzle(__float_as_int(x), IMM));
}
// sum across the 16-lane subgroup (xor 1,2,4,8; stays within 32-lane halves)
__device__ __forceinline__ float red16(float x) {
  x += swzf<0x041F>(x);
  x += swzf<0x081F>(x);
  x += swzf<0x101F>(x);
  x += swzf<0x201F>(x);
  return x;
}
__device__ __forceinline__ float redmax16(float x) {
  x = fmaxf(x, swzf<0x041F>(x));
  x = fmaxf(x, swzf<0x081F>(x));
  x = fmaxf(x, swzf<0x101F>(x));
  x = fmaxf(x, swzf<0x201F>(x));
  return x;
}

__global__ __launch_bounds__(512) void markowitz_kernel(
    const float* __restrict__ rets, const float* __restrict__ cov,
    const float* __restrict__ gam,  const float* __restrict__ alp,
    float* __restrict__ out)
{
  __shared__ char smem[LDS_BYTES] __attribute__((aligned(16)));
  float* STG = (float*)smem;
  f16*   CH  = (f16*)(smem + OFF_CH);
  f16*   CL  = (f16*)(smem + OFF_CL);

  const int b    = blockIdx.x;
  const int t    = threadIdx.x;
  const int lane = t & 63;
  const int wv   = t >> 6;          // wave 0..7
  const int lm   = lane & 15;       // column-within-tile owner index
  const int hq   = lane >> 4;       // row-subgroup index

  const float g  = gam[b];
  const float aa = fabsf(alp[b]);
  const float* __restrict__ C = cov + (size_t)b * (NA * NA);

  // Row-publisher lanes: lm in [4*hq, 4*hq+4) -> rows 16*wv+lm, 16*(wv+8)+lm
  const bool mk = ((lm >> 2) == hq);
  const int  cw = lm & 3;

  // ===== Phase 1: Q = (gC)^T(gC) + |a|I, ~f32-exact via compensated f16 syrk =====
  // acc[ii][J][p] = Q[16*(wv+8ii) + 4*hq + p][16*J + lm]   (m89 C/D layout)
  f32x4 acc[2][16];
  #pragma unroll
  for (int i = 0; i < 2; ++i)
    #pragma unroll
    for (int j = 0; j < 16; ++j)
      acc[i][j] = f32x4{0.f, 0.f, 0.f, 0.f};

  #pragma unroll 1
  for (int kb = 0; kb < 16; ++kb) {
    { // stage 16x256 f32 (gamma-folded), coalesced
      const int kk = t >> 5;          // 0..15
      const int ib = (t & 31) << 3;   // 0,8,...,248
      const float* src = C + (size_t)(kb * 16 + kk) * NA + ib;
      float* dst = STG + kk * CSTR + ib;
      float4 c0 = *(const float4*)(src);
      float4 c1 = *(const float4*)(src + 4);
      *(float4*)(dst)     = make_float4(c0.x * g, c0.y * g, c0.z * g, c0.w * g);
      *(float4*)(dst + 4) = make_float4(c1.x * g, c1.y * g, c1.z * g, c1.w * g);
    }
    __syncthreads();
    { // transpose + hi/lo split into C^T tiles (256 cols x 16 k)
      const int ti = t & 255;
      const int th = t >> 8;          // k-half 0/1
      f16x8 vh, vlo;
      #pragma unroll
      for (int s2 = 0; s2 < 8; ++s2) {
        const float x = STG[(8 * th + s2) * CSTR + ti];
        const f16 h = (f16)x;
        vh[s2]  = h;
        vlo[s2] = (f16)(x - (float)h);   // exact residual
      }
      *(f16x8*)(CH + ti * TSTR + 8 * th) = vh;
      *(f16x8*)(CL + ti * TSTR + 8 * th) = vlo;
    }
    __syncthreads();
    // Q += H^T H + H^T L + L^T H  (L^T L ~ 2^-22, negligible)
    #pragma unroll
    for (int ii = 0; ii < 2; ++ii) {
      const int I = wv + 8 * ii;
      const f16x4 aH = *(const f16x4*)(CH + (16 * I + lm) * TSTR + 4 * hq);
      const f16x4 aL = *(const f16x4*)(CL + (16 * I + lm) * TSTR + 4 * hq);
      #pragma unroll
      for (int J = 0; J < 16; ++J) {
        const f16x4 bH = *(const f16x4*)(CH + (16 * J + lm) * TSTR + 4 * hq);
        const f16x4 bL = *(const f16x4*)(CL + (16 * J + lm) * TSTR + 4 * hq);
        acc[ii][J] = __builtin_amdgcn_mfma_f32_16x16x16f16(aH, bH, acc[ii][J], 0, 0, 0);
        acc[ii][J] = __builtin_amdgcn_mfma_f32_16x16x16f16(aH, bL, acc[ii][J], 0, 0, 0);
        acc[ii][J] = __builtin_amdgcn_mfma_f32_16x16x16f16(aL, bH, acc[ii][J], 0, 0, 0);
      }
    }
  }

  // add |alpha| to the diagonal (row==col <=> J==I and lm==4*hq+p)
  #pragma unroll
  for (int J = 0; J < 16; ++J) {
    #pragma unroll
    for (int p = 0; p < 4; ++p) {
      if (J == wv     && lm == 4 * hq + p) acc[0][J][p] += aa;
      if (J == wv + 8 && lm == 4 * hq + p) acc[1][J][p] += aa;
    }
  }

  // Per-lane column state (columns {16*j + lm}), all in registers.
  float rr[16];
  #pragma unroll
  for (int j = 0; j < 16; ++j) rr[j] = rets[b * NA + 16 * j + lm];

  float z[16];
  #pragma unroll
  for (int j = 0; j < 16; ++j) z[j] = 1.f;   // power-iteration b0 = ones

  // matvec from register z; after reduce, all 16 lanes of a (wv,hq) group
  // hold y for rows {16*(wv+8ii)+4*hq+c}.
  auto matvec = [&](f32x4& y0, f32x4& y1) {
    y0 = f32x4{0.f, 0.f, 0.f, 0.f};
    y1 = f32x4{0.f, 0.f, 0.f, 0.f};
    #pragma unroll
    for (int J = 0; J < 16; ++J) {
      #pragma unroll
      for (int c = 0; c < 4; ++c) {
        y0[c] += acc[0][J][c] * z[J];
        y1[c] += acc[1][J][c] * z[J];
      }
    }
    #pragma unroll
    for (int c = 0; c < 4; ++c) { y0[c] = red16(y0[c]); y1[c] = red16(y1[c]); }
  };

  // publish y rows (only mk lanes): YY[16*wv+lm], YY[16*(wv+8)+lm]
  auto publish = [&](float* YYp, const f32x4& y0, const f32x4& y1) {
    if (mk) {
      const float ya = (cw == 0) ? y0[0] : (cw == 1) ? y0[1] : (cw == 2) ? y0[2] : y0[3];
      const float yb = (cw == 0) ? y1[0] : (cw == 1) ? y1[1] : (cw == 2) ? y1[2] : y1[3];
      YYp[16 * wv + lm]       = ya;
      YYp[16 * (wv + 8) + lm] = yb;
    }
  };

  // ===== Phase 2: power iteration + Rayleigh step size (1 barrier/iter) =====
  float step;
  {
    #pragma unroll 1
    for (int pi = 0; pi < POWER_ITERS; ++pi) {
      f32x4 y0, y1; matvec(y0, y1);
      float* YYp = (float*)(smem + ((pi & 1) ? OFF_YY1 : OFF_YY0));
      publish(YYp, y0, y1);
      __syncthreads();
      float yv[16];
      float nrm = 0.f;
      #pragma unroll
      for (int j = 0; j < 16; ++j) { yv[j] = YYp[16 * j + lm]; nrm += yv[j] * yv[j]; }
      nrm = red16(nrm);                       // sum over all 256 (16 lm-lanes)
      const float rb = 1.f / (sqrtf(nrm) + 1e-12f);
      #pragma unroll
      for (int j = 0; j < 16; ++j) z[j] = yv[j] * rb;
    }
    // lambda = b^T Q b  (POWER_ITERS is even -> buffer 0; prev iter used 1)
    f32x4 y0, y1; matvec(y0, y1);
    float* YYp = (float*)(smem + OFF_YY0);
    publish(YYp, y0, y1);
    __syncthreads();
    float lam = 0.f;
    #pragma unroll
    for (int j = 0; j < 16; ++j) lam += z[j] * YYp[16 * j + lm];
    lam = red16(lam);
    step = 1.f / (2.f * lam + 1e-6f);
  }

  // ===== Phase 3: FISTA (1 barrier/iter, state in registers) =====
  float wo[16];
  #pragma unroll
  for (int j = 0; j < 16; ++j) { z[j] = 1.f / 256.f; wo[j] = 1.f / 256.f; }
  float tt = 1.f;
  float tauw = 1e30f;

  #pragma unroll 1
  for (int it = 0; it < PGD_ITERS; ++it) {
    f32x4 y0, y1; matvec(y0, y1);
    // it=0 -> YY1 (lambda phase used YY0); alternates thereafter
    float* YYp = (float*)(smem + ((it & 1) ? OFF_YY0 : OFF_YY1));
    publish(YYp, y0, y1);
    __syncthreads();

    float v[16];
    #pragma unroll
    for (int j = 0; j < 16; ++j) {
      const float yv = YYp[16 * j + lm];
      v[j] = z[j] - step * (2.f * yv - rr[j]);
    }

    // Projection onto {w: sum=1, 0<=w<=1}; wave-redundant (hq groups hold
    // identical data -> bitwise-uniform tau). Bracket [max(v)-1, max(v)].
    float lo = -1e30f, hi = 1e30f;
    float tau = tauw;
    #pragma unroll 1
    for (int nit = 0; nit < 12; ++nit) {
      float s = 0.f, kc = 0.f;
      #pragma unroll
      for (int j = 0; j < 16; ++j) {
        const float x = v[j] - tau;
        s  += fminf(fmaxf(x, 0.f), 1.0f);
        kc += (x > 0.f && x < 1.0f) ? 1.f : 0.f;
      }
      s  = red16(s);
      kc = red16(kc);
      if (nit == 0) {
        float pm = v[0];
        #pragma unroll
        for (int j = 1; j < 16; ++j) pm = fmaxf(pm, v[j]);
        pm = redmax16(pm);
        lo = pm - 1.0f; hi = pm;
        if (!(tau > lo && tau < hi)) { tau = 0.5f * (lo + hi); continue; }
      }
      const float f = s - 1.f;
      if (fabsf(f) <= 1e-5f) break;           // achievable in f32
      if (f > 0.f) lo = tau; else hi = tau;
      if (hi - lo < 1e-7f) break;
      const float tn = (kc > 0.5f) ? (tau + f / kc) : (0.5f * (lo + hi));
      const float tc = (tn > lo && tn < hi) ? tn : 0.5f * (lo + hi);
      if (tc == tau) break;                   // numerical fixed point
      tau = tc;
    }
    tauw = tau;

    const float tnew = 0.5f * (1.f + sqrtf(1.f + 4.f * tt * tt));
    const float coef = (tt - 1.f) / tnew;
    #pragma unroll
    for (int j = 0; j < 16; ++j) {
      const float wn = fminf(fmaxf(v[j] - tau, 0.f), 1.0f);
      z[j]  = wn + coef * (wn - wo[j]);
      wo[j] = wn;
    }
    tt = tnew;
  }

  // Output f32; wave 0's hq=0 subgroup holds every column once.
  if (wv == 0 && lane < 16) {
    #pragma unroll
    for (int j = 0; j < 16; ++j) out[(size_t)b * NA + 16 * j + lane] = wo[j];
  }
}

extern "C" void kernel_launch(void* const* d_in, const int* in_sizes, int n_in,
                              void* d_out, int out_size, void* d_ws, size_t ws_size,
                              hipStream_t stream) {
  (void)in_sizes; (void)n_in; (void)out_size; (void)d_ws; (void)ws_size;
  const float* rets = (const float*)d_in[0];
  const float* cov  = (const float*)d_in[1];
  const float* gam  = (const float*)d_in[2];
  const float* alp  = (const float*)d_in[3];
  float* out = (float*)d_out;
  hipLaunchKernelGGL(markowitz_kernel, dim3(NS), dim3(512), 0, stream,
                     rets, cov, gam, alp, out);
}

// Round 10
// 1849.937 us; speedup vs baseline: 2.7747x; 1.6161x over previous
//
#include <hip/hip_runtime.h>

#define NS 512
#define NA 256
#define PGD_ITERS 300
#define POWER_ITERS 30

typedef _Float16 f16;
typedef __attribute__((ext_vector_type(4))) _Float16 f16x4;
typedef __attribute__((ext_vector_type(8))) _Float16 f16x8;
typedef __attribute__((ext_vector_type(4))) float f32x4;

// LDS layout (bytes). STG/CH/CL only live during the syrk; YY0/YY1 are the
// double-buffered y-exchange (1 KiB each) used by power + FISTA phases.
#define CSTR 260            // f32 staging row stride (elems)
#define TSTR 24             // f16 C^T tile row stride (elems) = 48 B
#define OFF_CH  16640       // STG: 16*260*4
#define OFF_CL  28928       // CH:  256*24*2
#define OFF_YY0 41216       // CL:  256*24*2
#define OFF_YY1 42240       // YY0: 256 f32
#define LDS_BYTES 43264     // YY1: 256 f32

// ---- cross-lane primitives ----
// DPP rotate-add within each 16-lane row: pure VALU, no DS-pipe traffic.
// SAFETY INVARIANT: call sites must have FULL exec (all 64 lanes active) —
// DPP reads from exec-off lanes return 0 (bound_ctrl) and corrupt the sum.
// All control flow around these is made wave-uniform via rfl().
template<int CTRL>
__device__ __forceinline__ float dpp_add(float x) {
  const int r = __builtin_amdgcn_update_dpp(0, __float_as_int(x), CTRL, 0xF, 0xF, true);
  return x + __int_as_float(r);
}
template<int CTRL>
__device__ __forceinline__ float dpp_max(float x) {
  const int r = __builtin_amdgcn_update_dpp(0, __float_as_int(x), CTRL, 0xF, 0xF, true);
  return fmaxf(x, __int_as_float(r));
}
// full 16-group sum/max via rotation doubling (row_ror 1,2,4,8)
__device__ __forceinline__ float red16(float x) {
  x = dpp_add<0x121>(x);  // row_ror:1
  x = dpp_add<0x122>(x);  // row_ror:2
  x = dpp_add<0x124>(x);  // row_ror:4
  x = dpp_add<0x128>(x);  // row_ror:8
  return x;
}
__device__ __forceinline__ float redmax16(float x) {
  x = dpp_max<0x121>(x);
  x = dpp_max<0x122>(x);
  x = dpp_max<0x124>(x);
  x = dpp_max<0x128>(x);
  return x;
}
// uniform broadcast: first-active-lane value into an SGPR (all branches on
// rfl() results are wave-uniform -> no divergence around DPP sites)
__device__ __forceinline__ float rfl(float x) {
  return __int_as_float(__builtin_amdgcn_readfirstlane(__float_as_int(x)));
}

__global__ __launch_bounds__(512) void markowitz_kernel(
    const float* __restrict__ rets, const float* __restrict__ cov,
    const float* __restrict__ gam,  const float* __restrict__ alp,
    float* __restrict__ out)
{
  __shared__ char smem[LDS_BYTES] __attribute__((aligned(16)));
  float* STG = (float*)smem;
  f16*   CH  = (f16*)(smem + OFF_CH);
  f16*   CL  = (f16*)(smem + OFF_CL);

  const int b    = blockIdx.x;
  const int t    = threadIdx.x;
  const int lane = t & 63;
  const int wv   = t >> 6;          // wave 0..7
  const int lm   = lane & 15;       // column-within-tile owner index
  const int hq   = lane >> 4;       // row-subgroup index

  const float g  = gam[b];
  const float aa = fabsf(alp[b]);
  const float* __restrict__ C = cov + (size_t)b * (NA * NA);

  // Row-publisher lanes: lm in [4*hq, 4*hq+4) -> rows 16*wv+lm, 16*(wv+8)+lm
  const bool mk = ((lm >> 2) == hq);
  const int  cw = lm & 3;

  // ===== Phase 1: Q = (gC)^T(gC) + |a|I, ~f32-exact via compensated f16 syrk =====
  // acc[ii][J][p] = Q[16*(wv+8ii) + 4*hq + p][16*J + lm]   (m89 C/D layout)
  f32x4 acc[2][16];
  #pragma unroll
  for (int i = 0; i < 2; ++i)
    #pragma unroll
    for (int j = 0; j < 16; ++j)
      acc[i][j] = f32x4{0.f, 0.f, 0.f, 0.f};

  #pragma unroll 1
  for (int kb = 0; kb < 16; ++kb) {
    { // stage 16x256 f32 (gamma-folded), coalesced
      const int kk = t >> 5;          // 0..15
      const int ib = (t & 31) << 3;   // 0,8,...,248
      const float* src = C + (size_t)(kb * 16 + kk) * NA + ib;
      float* dst = STG + kk * CSTR + ib;
      float4 c0 = *(const float4*)(src);
      float4 c1 = *(const float4*)(src + 4);
      *(float4*)(dst)     = make_float4(c0.x * g, c0.y * g, c0.z * g, c0.w * g);
      *(float4*)(dst + 4) = make_float4(c1.x * g, c1.y * g, c1.z * g, c1.w * g);
    }
    __syncthreads();
    { // transpose + hi/lo split into C^T tiles (256 cols x 16 k)
      const int ti = t & 255;
      const int th = t >> 8;          // k-half 0/1
      f16x8 vh, vlo;
      #pragma unroll
      for (int s2 = 0; s2 < 8; ++s2) {
        const float x = STG[(8 * th + s2) * CSTR + ti];
        const f16 h = (f16)x;
        vh[s2]  = h;
        vlo[s2] = (f16)(x - (float)h);   // exact residual
      }
      *(f16x8*)(CH + ti * TSTR + 8 * th) = vh;
      *(f16x8*)(CL + ti * TSTR + 8 * th) = vlo;
    }
    __syncthreads();
    // Q += H^T H + H^T L + L^T H  (L^T L ~ 2^-22, negligible)
    #pragma unroll
    for (int ii = 0; ii < 2; ++ii) {
      const int I = wv + 8 * ii;
      const f16x4 aH = *(const f16x4*)(CH + (16 * I + lm) * TSTR + 4 * hq);
      const f16x4 aL = *(const f16x4*)(CL + (16 * I + lm) * TSTR + 4 * hq);
      #pragma unroll
      for (int J = 0; J < 16; ++J) {
        const f16x4 bH = *(const f16x4*)(CH + (16 * J + lm) * TSTR + 4 * hq);
        const f16x4 bL = *(const f16x4*)(CL + (16 * J + lm) * TSTR + 4 * hq);
        acc[ii][J] = __builtin_amdgcn_mfma_f32_16x16x16f16(aH, bH, acc[ii][J], 0, 0, 0);
        acc[ii][J] = __builtin_amdgcn_mfma_f32_16x16x16f16(aH, bL, acc[ii][J], 0, 0, 0);
        acc[ii][J] = __builtin_amdgcn_mfma_f32_16x16x16f16(aL, bH, acc[ii][J], 0, 0, 0);
      }
    }
  }

  // add |alpha| to the diagonal (row==col <=> J==I and lm==4*hq+p)
  #pragma unroll
  for (int J = 0; J < 16; ++J) {
    #pragma unroll
    for (int p = 0; p < 4; ++p) {
      if (J == wv     && lm == 4 * hq + p) acc[0][J][p] += aa;
      if (J == wv + 8 && lm == 4 * hq + p) acc[1][J][p] += aa;
    }
  }

  // Per-lane column state (columns {16*j + lm}), all in registers.
  float rr[16];
  #pragma unroll
  for (int j = 0; j < 16; ++j) rr[j] = rets[b * NA + 16 * j + lm];

  float z[16];
  #pragma unroll
  for (int j = 0; j < 16; ++j) z[j] = 1.f;   // power-iteration b0 = ones

  // matvec from register z; after reduce, all 16 lanes of a (wv,hq) group
  // hold y for rows {16*(wv+8ii)+4*hq+c}. Full-exec call sites only.
  auto matvec = [&](f32x4& y0, f32x4& y1) {
    y0 = f32x4{0.f, 0.f, 0.f, 0.f};
    y1 = f32x4{0.f, 0.f, 0.f, 0.f};
    #pragma unroll
    for (int J = 0; J < 16; ++J) {
      #pragma unroll
      for (int c = 0; c < 4; ++c) {
        y0[c] += acc[0][J][c] * z[J];
        y1[c] += acc[1][J][c] * z[J];
      }
    }
    #pragma unroll
    for (int c = 0; c < 4; ++c) { y0[c] = red16(y0[c]); y1[c] = red16(y1[c]); }
  };

  // publish y rows (only mk lanes): YY[16*wv+lm], YY[16*(wv+8)+lm]
  auto publish = [&](float* YYp, const f32x4& y0, const f32x4& y1) {
    if (mk) {
      const float ya = (cw == 0) ? y0[0] : (cw == 1) ? y0[1] : (cw == 2) ? y0[2] : y0[3];
      const float yb = (cw == 0) ? y1[0] : (cw == 1) ? y1[1] : (cw == 2) ? y1[2] : y1[3];
      YYp[16 * wv + lm]       = ya;
      YYp[16 * (wv + 8) + lm] = yb;
    }
  };

  // ===== Phase 2: power iteration + Rayleigh step size (1 barrier/iter) =====
  float step;
  {
    #pragma unroll 1
    for (int pi = 0; pi < POWER_ITERS; ++pi) {
      f32x4 y0, y1; matvec(y0, y1);
      float* YYp = (float*)(smem + ((pi & 1) ? OFF_YY1 : OFF_YY0));
      publish(YYp, y0, y1);
      __syncthreads();
      float yv[16];
      float nrm = 0.f;
      #pragma unroll
      for (int j = 0; j < 16; ++j) { yv[j] = YYp[16 * j + lm]; nrm += yv[j] * yv[j]; }
      nrm = rfl(red16(nrm));                  // uniform across all lanes/waves
      const float rb = 1.f / (sqrtf(nrm) + 1e-12f);
      #pragma unroll
      for (int j = 0; j < 16; ++j) z[j] = yv[j] * rb;   // bitwise-uniform copies
    }
    // lambda = b^T Q b  (POWER_ITERS is even -> buffer 0; prev iter used 1)
    f32x4 y0, y1; matvec(y0, y1);
    float* YYp = (float*)(smem + OFF_YY0);
    publish(YYp, y0, y1);
    __syncthreads();
    float lam = 0.f;
    #pragma unroll
    for (int j = 0; j < 16; ++j) lam += z[j] * YYp[16 * j + lm];
    lam = rfl(red16(lam));
    step = 1.f / (2.f * lam + 1e-6f);         // uniform
  }

  // ===== Phase 3: FISTA (1 barrier/iter, state in registers) =====
  float wo[16];
  #pragma unroll
  for (int j = 0; j < 16; ++j) { z[j] = 1.f / 256.f; wo[j] = 1.f / 256.f; }
  float tt = 1.f;
  float tauw = 1e30f;
  float kest = 32.f;     // persistent active-count (slope) estimate (uniform)

  #pragma unroll 1
  for (int it = 0; it < PGD_ITERS; ++it) {
    f32x4 y0, y1; matvec(y0, y1);
    // it=0 -> YY1 (lambda phase used YY0); alternates thereafter
    float* YYp = (float*)(smem + ((it & 1) ? OFF_YY0 : OFF_YY1));
    publish(YYp, y0, y1);
    __syncthreads();

    float v[16];
    #pragma unroll
    for (int j = 0; j < 16; ++j) {
      const float yv = YYp[16 * j + lm];
      v[j] = z[j] - step * (2.f * yv - rr[j]);  // uniform across duplicates
    }

    // Projection onto {w: sum=1, 0<=w<=1}. Each lane evaluates its own 16
    // columns; red16 over the lm-row covers all 256; rfl() makes every
    // control value wave-uniform -> no divergence -> DPP sites full-exec.
    // Zero DS ops. Bracket [max(v)-1, max(v)]; bracket-safeguarded secant.
    float lo = -1e30f, hi = 1e30f;
    float tau = tauw;
    float fprev = 0.f, tprev = 0.f;
    bool have = false;
    #pragma unroll 1
    for (int nit = 0; nit < 16; ++nit) {
      float sp = 0.f;
      #pragma unroll
      for (int j = 0; j < 16; ++j)
        sp += fminf(fmaxf(v[j] - tau, 0.f), 1.f);
      const float s = rfl(red16(sp));         // uniform total
      if (nit == 0) {
        float pm = v[0];
        #pragma unroll
        for (int j = 1; j < 16; ++j) pm = fmaxf(pm, v[j]);
        pm = rfl(redmax16(pm));               // uniform max
        lo = pm - 1.0f; hi = pm;
        if (!(tau > lo && tau < hi)) { tau = 0.5f * (lo + hi); continue; }
      }
      const float f = s - 1.f;
      if (fabsf(f) <= 1e-5f) break;
      if (f > 0.f) lo = tau; else hi = tau;
      if (hi - lo < 1e-7f) break;
      float kc = have ? ((f - fprev) / (tprev - tau)) : kest;  // secant slope
      if (!(kc > 0.5f)) kc = kest;            // plateau / first-eval fallback
      const float tn = tau + f / kc;
      fprev = f; tprev = tau; have = true;
      kest = fmaxf(kc, 1.f);
      const float tc = (tn > lo && tn < hi) ? tn : 0.5f * (lo + hi);
      if (tc == tau) break;                   // numerical fixed point
      tau = tc;
    }
    tauw = tau;

    const float tnew = 0.5f * (1.f + sqrtf(1.f + 4.f * tt * tt));
    const float coef = (tt - 1.f) / tnew;
    #pragma unroll
    for (int j = 0; j < 16; ++j) {
      const float wn = fminf(fmaxf(v[j] - tau, 0.f), 1.0f);
      z[j]  = wn + coef * (wn - wo[j]);
      wo[j] = wn;
    }
    tt = tnew;
  }

  // Output f32; wave 0's hq=0 subgroup holds every column once.
  if (wv == 0 && lane < 16) {
    #pragma unroll
    for (int j = 0; j < 16; ++j) out[(size_t)b * NA + 16 * j + lane] = wo[j];
  }
}

extern "C" void kernel_launch(void* const* d_in, const int* in_sizes, int n_in,
                              void* d_out, int out_size, void* d_ws, size_t ws_size,
                              hipStream_t stream) {
  (void)in_sizes; (void)n_in; (void)out_size; (void)d_ws; (void)ws_size;
  const float* rets = (const float*)d_in[0];
  const float* cov  = (const float*)d_in[1];
  const float* gam  = (const float*)d_in[2];
  const float* alp  = (const float*)d_in[3];
  float* out = (float*)d_out;
  hipLaunchKernelGGL(markowitz_kernel, dim3(NS), dim3(512), 0, stream,
                     rets, cov, gam, alp, out);
}